// Round 5
// baseline (290.375 us; speedup 1.0000x reference)
//
#include <hip/hip_runtime.h>
#include <hip/hip_bf16.h>

#define N_NODES 100000
#define N_EDGES 1600000
#define IN_CH 256
#define OUT_CH 128

#define BSZ 256            // nodes per bucket (power of 2)
#define NBUCK 391          // ceil(N_NODES / BSZ)
#define BCAP 4736          // bucket capacity: mean 4096, sd ~64 -> 10 sigma headroom
#define CSC 4096           // edges per block, scatter
#define SCB 391            // scatter blocks = ceil(N_EDGES / CSC)
#define PREPB 64           // prep-W blocks (64 x 512 = 32768 elements)

#define GEMM_ROWS 64       // rows per block

typedef __attribute__((ext_vector_type(8))) short short8;
typedef __attribute__((ext_vector_type(4))) float floatx4;
typedef __attribute__((ext_vector_type(2))) float float2v;

union bfu { __hip_bfloat16 b; unsigned short u; };

__device__ inline unsigned short f2bf(float v) {
    bfu cv; cv.b = __float2bfloat16(v); return cv.u;
}
__device__ inline float bf2f(unsigned short u) {
    bfu cv; cv.u = u; return __bfloat162float(cv.b);
}

// unpack a packed bf16 pair and accumulate both channels with one v_pk_add_f32
__device__ inline void pkacc(float2v& acc, unsigned g) {
    float2v v;
    v.x = __uint_as_float(g << 16);
    v.y = __uint_as_float(g & 0xffff0000u);
    asm("v_pk_add_f32 %0, %1, %2" : "=v"(acc) : "v"(v), "v"(acc));
}

// ---------- fused: single-pass bucket scatter + W prep ----------
// Scatter (blocks 0..SCB-1): ONE pass over edges.  The LDS-histogram
// atomicAdd already returns each edge's local rank; stash (val,bk,rank) in
// registers (8 edges/thread, statically unrolled), reserve one global run
// per bucket, then write each edge directly to its final slot.  No edge
// re-read, no second atomic pass.
// Prep (blocks SCB..SCB+PREPB-1): W -> MFMA-fragment-packed split-bf16.
__global__ __launch_bounds__(512) void k_scatter_prep(const int* __restrict__ rows,
                                                      const int* __restrict__ cols,
                                                      int* __restrict__ bcursor,
                                                      unsigned* __restrict__ ebuf,
                                                      const float* __restrict__ W,
                                                      unsigned short* __restrict__ wb_hi,
                                                      unsigned short* __restrict__ wb_lo) {
    if (blockIdx.x >= SCB) {
        // ---- W prep part ----
        int t = (blockIdx.x - SCB) * 512 + threadIdx.x;   // 0..32767
        int j = t & 7;
        int lane = (t >> 3) & 63;
        int s = (t >> 9) & 7;
        int nt = t >> 12;
        int k = s * 32 + (lane >> 4) * 8 + j;
        int n = nt * 16 + (lane & 15);
        float w = W[k * OUT_CH + n];
        unsigned short hi = f2bf(w);
        wb_hi[t] = hi;
        wb_lo[t] = f2bf(w - bf2f(hi));
        return;
    }

    __shared__ int lcnt[NBUCK];
    __shared__ int lbase[NBUCK];
    int t = threadIdx.x;
    for (int i = t; i < NBUCK; i += 512) lcnt[i] = 0;
    __syncthreads();

    int s0 = blockIdx.x * CSC;
    int e1 = min(N_EDGES, s0 + CSC);

    unsigned val[8];
    int bkr[8], rk[8];
#pragma unroll
    for (int u = 0; u < 8; ++u) {
        int i = s0 + t + u * 512;
        bool p = i < e1;
        int c = p ? cols[i] : 0;
        int r = p ? rows[i] : 0;
        int bk = c >> 8;
        bkr[u] = bk;
        val[u] = ((unsigned)(c & (BSZ - 1)) << 17) | (unsigned)r;
        rk[u] = p ? atomicAdd(&lcnt[bk], 1) : 0;
    }
    __syncthreads();
    for (int i = t; i < NBUCK; i += 512) {
        int c = lcnt[i];
        lbase[i] = c ? atomicAdd(&bcursor[i], c) : 0;
    }
    __syncthreads();
#pragma unroll
    for (int u = 0; u < 8; ++u) {
        int i = s0 + t + u * 512;
        if (i < e1) ebuf[bkr[u] * BCAP + lbase[bkr[u]] + rk[u]] = val[u];
    }
}

// ---------- per-bucket fine sort + cnt/base/dinv, single edge pass ----------
// Rank comes from the histogram atomicAdd; after the prefix scan each stashed
// edge goes straight to its final es slot.  es = BYTE offsets into hbs.
__global__ __launch_bounds__(512) void pb_build(const unsigned* __restrict__ ebuf,
                                                const int* __restrict__ bcursor,
                                                int* __restrict__ cnt,
                                                int* __restrict__ base,
                                                float* __restrict__ dinv,
                                                int* __restrict__ es) {
    __shared__ int nh[BSZ];
    __shared__ int sc[BSZ];
    int t = threadIdx.x;
    int bk = blockIdx.x;
    int bb = bk * BCAP;
    int bc = bcursor[bk];
    if (t < BSZ) nh[t] = 0;
    __syncthreads();

    unsigned val[10];
    int rk[10];
#pragma unroll
    for (int u = 0; u < 10; ++u) {
        int i = t + u * 512;
        bool p = i < bc;
        unsigned v = p ? ebuf[bb + i] : 0u;
        val[u] = v;
        rk[u] = p ? atomicAdd(&nh[v >> 17], 1) : 0;
    }
    __syncthreads();
    if (t < BSZ) sc[t] = nh[t];
    __syncthreads();
    for (int off = 1; off < BSZ; off <<= 1) {
        int v = (t < BSZ && t >= off) ? sc[t - off] : 0;
        __syncthreads();
        if (t < BSZ) sc[t] += v;
        __syncthreads();
    }
    if (t < BSZ) {
        int node = bk * BSZ + t;
        if (node < N_NODES) {
            int c = nh[t];
            cnt[node] = c;
            base[node] = bb + sc[t] - c;
            dinv[node] = rsqrtf((float)(c + 1));
        }
    }
#pragma unroll
    for (int u = 0; u < 10; ++u) {
        int i = t + u * 512;
        if (i < bc) {
            unsigned v = val[u];
            int dl = v >> 17;
            es[bb + sc[dl] - nh[dl] + rk[u]] = (int)(v & 0x1FFFFu) << 8;   // byte offset
        }
    }
}

// ---------- h = x @ W  (fp32 in via split-bf16 MFMA), 64 rows/block ----------
// Coalesced conversion loads (32 consecutive lanes read one contiguous 1 KB
// row), padded LDS fragment layout (stride-68 short8, q2 stride 17).
// 64-row blocks halve per-block B-fragment L2 re-reads vs 32-row.
__global__ __launch_bounds__(512) void k_gemm(const float* __restrict__ x,
                                              const unsigned short* __restrict__ wb_hi,
                                              const unsigned short* __restrict__ wb_lo,
                                              const float* __restrict__ dinv,
                                              unsigned short* __restrict__ hbs) {
    __shared__ short8 xbh[4 * 8 * 68];   // 34816 B
    __shared__ short8 xbl[4 * 8 * 68];   // 34816 B
    int t = threadIdx.x;
    int wv = t >> 6;        // 0..7 = n-tile
    int lane = t & 63;
    int row0 = blockIdx.x * GEMM_ROWS;

    // B fragments (L2-resident): issue loads early
    short8 Bh[8], Bl[8];
    const short8* bhp = (const short8*)wb_hi + (size_t)wv * 8 * 64 + lane;
    const short8* blp = (const short8*)wb_lo + (size_t)wv * 8 * 64 + lane;
#pragma unroll
    for (int s = 0; s < 8; ++s) {
        Bh[s] = bhp[s * 64];
        Bl[s] = blp[s * 64];
    }

    // cooperative fp32 -> split-bf16 conversion, 4 chunks (of 8 floats) per thread
#pragma unroll
    for (int q = 0; q < 4; ++q) {
        int c = q * 512 + t;          // 0..2047
        int row = c >> 5;             // 0..63
        int cc  = c & 31;             // col chunk (8 floats)
        int gr = min(row0 + row, N_NODES - 1);   // clamp for tail block
        const float4* xp = (const float4*)(x + (size_t)gr * IN_CH + cc * 8);
        float4 v0 = xp[0];
        float4 v1 = xp[1];
        float xv[8] = {v0.x, v0.y, v0.z, v0.w, v1.x, v1.y, v1.z, v1.w};
        short8 hh, ll;
#pragma unroll
        for (int j = 0; j < 8; ++j) {
            unsigned short hi = f2bf(xv[j]);
            hh[j] = (short)hi;
            ll[j] = (short)f2bf(xv[j] - bf2f(hi));
        }
        int ms = row >> 4, r15 = row & 15, s = cc >> 2, q2 = cc & 3;
        int idx = (ms * 8 + s) * 68 + q2 * 17 + r15;
        xbh[idx] = hh;
        xbl[idx] = ll;
    }
    __syncthreads();

    int r15 = lane & 15;
    int quad = lane >> 4;
    int lidx = quad * 17 + r15;

    floatx4 acc[4];
#pragma unroll
    for (int ms = 0; ms < 4; ++ms) {
        acc[ms] = (floatx4){0.f, 0.f, 0.f, 0.f};
#pragma unroll
        for (int s = 0; s < 8; ++s) {
            short8 ah = xbh[(ms * 8 + s) * 68 + lidx];
            short8 al = xbl[(ms * 8 + s) * 68 + lidx];
            acc[ms] = __builtin_amdgcn_mfma_f32_16x16x32_bf16(ah, Bh[s], acc[ms], 0, 0, 0);
            acc[ms] = __builtin_amdgcn_mfma_f32_16x16x32_bf16(ah, Bl[s], acc[ms], 0, 0, 0);
            acc[ms] = __builtin_amdgcn_mfma_f32_16x16x32_bf16(al, Bh[s], acc[ms], 0, 0, 0);
        }
    }

#pragma unroll
    for (int ms = 0; ms < 4; ++ms)
#pragma unroll
        for (int r = 0; r < 4; ++r) {
            int row = row0 + ms * 16 + quad * 4 + r;
            if (row < N_NODES) {
                size_t idx = (size_t)row * OUT_CH + wv * 16 + r15;
                hbs[idx] = f2bf(acc[ms][r] * dinv[row]);
            }
        }
}

// ---------- fused gather-aggregate + minmax scale + L2 normalize ----------
// 4 nodes per wave, 16 lanes per node, dwordx4 gathers (one 256 B row per
// group per instruction).  Pinned at the fabric compulsory-miss floor
// (~189 MB fetch, ~3.7 TB/s) -- frozen since R3.
__global__ __launch_bounds__(256) void k_agg_fin(const unsigned short* __restrict__ hbs,
                                                 const float* __restrict__ dinv,
                                                 const int* __restrict__ es,
                                                 const int* __restrict__ base,
                                                 const int* __restrict__ cnt,
                                                 const float* __restrict__ b,
                                                 float* __restrict__ out) {
    int t = threadIdx.x;
    int lane = t & 63;
    int ll = lane & 15;           // lane within node group
    int node = blockIdx.x * 16 + (t >> 4);

    const char* hb = (const char*)hbs;
    int lane_byte = ll << 4;
    int bidx = (lane & 48) << 2;  // bpermute byte index of group's lane 0

    float dn = dinv[node];
    int d  = cnt[node];
    int st = base[node];

    float4 bv0 = ((const float4*)b)[ll * 2];
    float4 bv1 = ((const float4*)b)[ll * 2 + 1];

    // self row (pre-scaled by dinv[node])
    uint4 gs = *(const uint4*)(hb + ((size_t)node << 8) + lane_byte);
    float2v acc[4];
    acc[0].x = __uint_as_float(gs.x << 16); acc[0].y = __uint_as_float(gs.x & 0xffff0000u);
    acc[1].x = __uint_as_float(gs.y << 16); acc[1].y = __uint_as_float(gs.y & 0xffff0000u);
    acc[2].x = __uint_as_float(gs.z << 16); acc[2].y = __uint_as_float(gs.z & 0xffff0000u);
    acc[3].x = __uint_as_float(gs.w << 16); acc[3].y = __uint_as_float(gs.w & 0xffff0000u);

    int dm = d;
    dm = max(dm, __shfl_xor(dm, 16, 64));
    dm = max(dm, __shfl_xor(dm, 32, 64));
    int iters = __builtin_amdgcn_readfirstlane((dm + 15) >> 4);

    const int zoff = N_NODES << 8;   // zero row byte offset

    for (int it = 0; it < iters; ++it) {
        int jb = it << 4;
        int off = zoff;
        if (jb + ll < d) off = es[st + jb + ll];

        uint4 ga[4], gb[4];
#pragma unroll
        for (int k = 0; k < 4; ++k) {
            int ro = __builtin_amdgcn_ds_bpermute(bidx + (k << 2), off);
            ga[k] = *(const uint4*)(hb + (unsigned)(ro + lane_byte));
        }
#pragma unroll
        for (int k = 0; k < 4; ++k) {
            int ro = __builtin_amdgcn_ds_bpermute(bidx + ((4 + k) << 2), off);
            gb[k] = *(const uint4*)(hb + (unsigned)(ro + lane_byte));
        }
#pragma unroll
        for (int k = 0; k < 4; ++k) {
            pkacc(acc[0], ga[k].x); pkacc(acc[1], ga[k].y);
            pkacc(acc[2], ga[k].z); pkacc(acc[3], ga[k].w);
        }
#pragma unroll
        for (int k = 0; k < 4; ++k) {
            int ro = __builtin_amdgcn_ds_bpermute(bidx + ((8 + k) << 2), off);
            ga[k] = *(const uint4*)(hb + (unsigned)(ro + lane_byte));
        }
#pragma unroll
        for (int k = 0; k < 4; ++k) {
            pkacc(acc[0], gb[k].x); pkacc(acc[1], gb[k].y);
            pkacc(acc[2], gb[k].z); pkacc(acc[3], gb[k].w);
        }
#pragma unroll
        for (int k = 0; k < 4; ++k) {
            int ro = __builtin_amdgcn_ds_bpermute(bidx + ((12 + k) << 2), off);
            gb[k] = *(const uint4*)(hb + (unsigned)(ro + lane_byte));
        }
#pragma unroll
        for (int k = 0; k < 4; ++k) {
            pkacc(acc[0], ga[k].x); pkacc(acc[1], ga[k].y);
            pkacc(acc[2], ga[k].z); pkacc(acc[3], ga[k].w);
        }
#pragma unroll
        for (int k = 0; k < 4; ++k) {
            pkacc(acc[0], gb[k].x); pkacc(acc[1], gb[k].y);
            pkacc(acc[2], gb[k].z); pkacc(acc[3], gb[k].w);
        }
    }

    float v[8];
    v[0] = dn * acc[0].x + bv0.x;  v[1] = dn * acc[0].y + bv0.y;
    v[2] = dn * acc[1].x + bv0.z;  v[3] = dn * acc[1].y + bv0.w;
    v[4] = dn * acc[2].x + bv1.x;  v[5] = dn * acc[2].y + bv1.y;
    v[6] = dn * acc[3].x + bv1.z;  v[7] = dn * acc[3].y + bv1.w;

    float lmin = v[0], lmax = v[0];
#pragma unroll
    for (int i = 1; i < 8; ++i) { lmin = fminf(lmin, v[i]); lmax = fmaxf(lmax, v[i]); }
#pragma unroll
    for (int m = 8; m; m >>= 1) {
        lmin = fminf(lmin, __shfl_xor(lmin, m, 64));
        lmax = fmaxf(lmax, __shfl_xor(lmax, m, 64));
    }
    float scale = 1.0f / (lmax - lmin);
    float z[8];
    float ss = 0.f;
#pragma unroll
    for (int i = 0; i < 8; ++i) { z[i] = (v[i] - lmin) * scale; ss += z[i] * z[i]; }
#pragma unroll
    for (int m = 8; m; m >>= 1) ss += __shfl_xor(ss, m, 64);
    float inv = 1.0f / fmaxf(sqrtf(ss), 1e-12f);

    float4 o0 = {z[0] * inv, z[1] * inv, z[2] * inv, z[3] * inv};
    float4 o1 = {z[4] * inv, z[5] * inv, z[6] * inv, z[7] * inv};
    float4* op = (float4*)(out + (size_t)node * OUT_CH);
    op[ll * 2] = o0;
    op[ll * 2 + 1] = o1;
}

extern "C" void kernel_launch(void* const* d_in, const int* in_sizes, int n_in,
                              void* d_out, int out_size, void* d_ws, size_t ws_size,
                              hipStream_t stream) {
    const float* x = (const float*)d_in[0];        // fp32 [N, 256]
    const int* ei = (const int*)d_in[1];           // int32 [2, E]
    const float* W = (const float*)d_in[2];        // fp32 [256, 128]
    const float* b = (const float*)d_in[3];        // fp32 [128]
    float* out = (float*)d_out;                    // fp32 [N, 128]

    char* ws = (char*)d_ws;
    size_t o = 0;
    auto alloc = [&](size_t bytes) { void* p = ws + o; o = (o + bytes + 255) & ~(size_t)255; return p; };
    float* dinv    = (float*)alloc((size_t)N_NODES * 4);
    int*   cnt     = (int*)  alloc((size_t)N_NODES * 4);
    int*   base    = (int*)  alloc((size_t)N_NODES * 4);
    int*   bcursor = (int*)  alloc(NBUCK * 4);
    unsigned short* wb_hi = (unsigned short*)alloc((size_t)IN_CH * OUT_CH * 2);
    unsigned short* wb_lo = (unsigned short*)alloc((size_t)IN_CH * OUT_CH * 2);
    unsigned short* hbs = (unsigned short*)alloc((size_t)(N_NODES + 1) * OUT_CH * 2);  // +1 zero row
    unsigned* ebuf = (unsigned*)alloc((size_t)NBUCK * BCAP * 4);
    int*   es      = (int*)  alloc((size_t)NBUCK * BCAP * 4);

    const int* rows = ei;
    const int* cols = ei + N_EDGES;

    // zero bucket cursors + gather zero-row (stream-ordered before users)
    hipMemsetAsync(bcursor, 0, NBUCK * sizeof(int), stream);
    hipMemsetAsync(hbs + (size_t)N_NODES * OUT_CH, 0, OUT_CH * 2, stream);

    // fused: single-pass bucket scatter + W prep
    k_scatter_prep<<<SCB + PREPB, 512, 0, stream>>>(rows, cols, bcursor, ebuf,
                                                    W, wb_hi, wb_lo);

    // per-bucket fine sort + cnt/base/dinv (single edge pass)
    pb_build<<<NBUCK, 512, 0, stream>>>(ebuf, bcursor, cnt, base, dinv, es);

    // GEMM (64 rows/block)
    k_gemm<<<(N_NODES + GEMM_ROWS - 1) / GEMM_ROWS, 512, 0, stream>>>(
        x, wb_hi, wb_lo, dinv, hbs);

    // fused aggregate + scale + normalize
    k_agg_fin<<<N_NODES / 16, 256, 0, stream>>>(hbs, dinv, es, base, cnt, b, out);
}

// Round 6
// 273.416 us; speedup vs baseline: 1.0620x; 1.0620x over previous
//
#include <hip/hip_runtime.h>
#include <hip/hip_bf16.h>

#define N_NODES 100000
#define N_EDGES 1600000
#define IN_CH 256
#define OUT_CH 128

#define BSZ 256            // nodes per bucket (power of 2)
#define NBUCK 391          // ceil(N_NODES / BSZ)
#define BCAP 4736          // bucket capacity: mean 4096, sd ~64 -> 10 sigma headroom
#define CSC 4096           // edges per block, scatter
#define SCB 391            // scatter blocks = ceil(N_EDGES / CSC)
#define PREPB 64           // init blocks (64 x 512 = 32768 W elements)

#define GEMM_ROWS 32       // rows per gemm block (32-row: 38 KB LDS -> 4 blocks/CU)
#define GEMB 3125          // N_NODES / GEMM_ROWS

typedef __attribute__((ext_vector_type(8))) short short8;
typedef __attribute__((ext_vector_type(4))) float floatx4;
typedef __attribute__((ext_vector_type(2))) float float2v;

union bfu { __hip_bfloat16 b; unsigned short u; };

__device__ inline unsigned short f2bf(float v) {
    bfu cv; cv.b = __float2bfloat16(v); return cv.u;
}
__device__ inline float bf2f(unsigned short u) {
    bfu cv; cv.u = u; return __bfloat162float(cv.b);
}

// acc += dnp * unpacked(g): one v_pk_fma_f32 for both channels
__device__ inline void pkfma(float2v& acc, unsigned g, float2v dnp) {
    float2v v;
    v.x = __uint_as_float(g << 16);
    v.y = __uint_as_float(g & 0xffff0000u);
    asm("v_pk_fma_f32 %0, %1, %2, %3" : "=v"(acc) : "v"(v), "v"(dnp), "v"(acc));
}

// ---------- init: W -> fragment-packed split-bf16, zero bcursor + zero-row ----------
__global__ __launch_bounds__(512) void k_init(const float* __restrict__ W,
                                              unsigned short* __restrict__ wb_hi,
                                              unsigned short* __restrict__ wb_lo,
                                              int* __restrict__ bcursor,
                                              unsigned* __restrict__ zrow) {
    int tid = threadIdx.x;
    if (blockIdx.x == 0 && tid < NBUCK) bcursor[tid] = 0;
    if (blockIdx.x == 1 && tid < 64) zrow[tid] = 0;   // 256 B zero row

    int t = blockIdx.x * 512 + tid;   // 0..32767
    int j = t & 7;
    int lane = (t >> 3) & 63;
    int s = (t >> 9) & 7;
    int nt = t >> 12;
    int k = s * 32 + (lane >> 4) * 8 + j;
    int n = nt * 16 + (lane & 15);
    float w = W[k * OUT_CH + n];
    unsigned short hi = f2bf(w);
    wb_hi[t] = hi;
    wb_lo[t] = f2bf(w - bf2f(hi));
}

// ---------- fused: single-pass bucket scatter || GEMM (independent work) ----------
// Blocks 0..SCB-1: edge scatter (one pass; rank from LDS-histogram atomicAdd).
// Blocks SCB..SCB+GEMB-1: h = x @ W via split-bf16 MFMA, hbs = bf16(h) UNSCALED
// (dinv is applied per-edge in k_agg_fin, which removes the CSR->gemm
// dependency and lets both run concurrently in this launch).
__global__ __launch_bounds__(512) void k_main(const int* __restrict__ rows,
                                              const int* __restrict__ cols,
                                              int* __restrict__ bcursor,
                                              unsigned* __restrict__ ebuf,
                                              const float* __restrict__ x,
                                              const unsigned short* __restrict__ wb_hi,
                                              const unsigned short* __restrict__ wb_lo,
                                              unsigned short* __restrict__ hbs) {
    __shared__ int lcnt[NBUCK];
    __shared__ int lbase[NBUCK];
    __shared__ short8 xbh[2 * 8 * 68];   // 17408 B
    __shared__ short8 xbl[2 * 8 * 68];   // 17408 B

    int t = threadIdx.x;

    if (blockIdx.x < SCB) {
        // ---- scatter path ----
        if (t < NBUCK) lcnt[t] = 0;
        __syncthreads();

        int s0 = blockIdx.x * CSC;
        int e1 = min(N_EDGES, s0 + CSC);

        unsigned val[8];
        int bkr[8], rk[8];
#pragma unroll
        for (int u = 0; u < 8; ++u) {
            int i = s0 + t + u * 512;
            bool p = i < e1;
            int c = p ? cols[i] : 0;
            int r = p ? rows[i] : 0;
            int bk = c >> 8;
            bkr[u] = bk;
            val[u] = ((unsigned)(c & (BSZ - 1)) << 17) | (unsigned)r;
            rk[u] = p ? atomicAdd(&lcnt[bk], 1) : 0;
        }
        __syncthreads();
        if (t < NBUCK) {
            int c = lcnt[t];
            lbase[t] = c ? atomicAdd(&bcursor[t], c) : 0;
        }
        __syncthreads();
#pragma unroll
        for (int u = 0; u < 8; ++u) {
            int i = s0 + t + u * 512;
            if (i < e1) ebuf[bkr[u] * BCAP + lbase[bkr[u]] + rk[u]] = val[u];
        }
        return;
    }

    // ---- gemm path ----
    int wv = t >> 6;        // 0..7 = n-tile
    int lane = t & 63;
    int row0 = (blockIdx.x - SCB) * GEMM_ROWS;

    short8 Bh[8], Bl[8];
    const short8* bhp = (const short8*)wb_hi + (size_t)wv * 8 * 64 + lane;
    const short8* blp = (const short8*)wb_lo + (size_t)wv * 8 * 64 + lane;
#pragma unroll
    for (int s = 0; s < 8; ++s) {
        Bh[s] = bhp[s * 64];
        Bl[s] = blp[s * 64];
    }

    // cooperative fp32 -> split-bf16 conversion, coalesced 1 KB-row loads
#pragma unroll
    for (int q = 0; q < 2; ++q) {
        int c = q * 512 + t;          // 0..1023
        int row = c >> 5;             // 0..31
        int cc  = c & 31;             // col chunk (8 floats)
        const float4* xp = (const float4*)(x + (size_t)(row0 + row) * IN_CH + cc * 8);
        float4 v0 = xp[0];
        float4 v1 = xp[1];
        float xv[8] = {v0.x, v0.y, v0.z, v0.w, v1.x, v1.y, v1.z, v1.w};
        short8 hh, ll;
#pragma unroll
        for (int j = 0; j < 8; ++j) {
            unsigned short hi = f2bf(xv[j]);
            hh[j] = (short)hi;
            ll[j] = (short)f2bf(xv[j] - bf2f(hi));
        }
        int ms = row >> 4, r15 = row & 15, s = cc >> 2, q2 = cc & 3;
        int idx = (ms * 8 + s) * 68 + q2 * 17 + r15;
        xbh[idx] = hh;
        xbl[idx] = ll;
    }
    __syncthreads();

    int r15 = lane & 15;
    int quad = lane >> 4;
    int lidx = quad * 17 + r15;

    floatx4 acc[2];
#pragma unroll
    for (int ms = 0; ms < 2; ++ms) {
        acc[ms] = (floatx4){0.f, 0.f, 0.f, 0.f};
#pragma unroll
        for (int s = 0; s < 8; ++s) {
            short8 ah = xbh[(ms * 8 + s) * 68 + lidx];
            short8 al = xbl[(ms * 8 + s) * 68 + lidx];
            acc[ms] = __builtin_amdgcn_mfma_f32_16x16x32_bf16(ah, Bh[s], acc[ms], 0, 0, 0);
            acc[ms] = __builtin_amdgcn_mfma_f32_16x16x32_bf16(ah, Bl[s], acc[ms], 0, 0, 0);
            acc[ms] = __builtin_amdgcn_mfma_f32_16x16x32_bf16(al, Bh[s], acc[ms], 0, 0, 0);
        }
    }

#pragma unroll
    for (int ms = 0; ms < 2; ++ms)
#pragma unroll
        for (int r = 0; r < 4; ++r) {
            int row = row0 + ms * 16 + quad * 4 + r;
            size_t idx = (size_t)row * OUT_CH + wv * 16 + r15;
            hbs[idx] = f2bf(acc[ms][r]);   // UNSCALED
        }
}

// ---------- per-bucket fine sort + cnt/base/dinv, single edge pass ----------
__global__ __launch_bounds__(512) void pb_build(const unsigned* __restrict__ ebuf,
                                                const int* __restrict__ bcursor,
                                                int* __restrict__ cnt,
                                                int* __restrict__ base,
                                                float* __restrict__ dinv,
                                                int* __restrict__ es) {
    __shared__ int nh[BSZ];
    __shared__ int sc[BSZ];
    int t = threadIdx.x;
    int bk = blockIdx.x;
    int bb = bk * BCAP;
    int bc = bcursor[bk];
    if (t < BSZ) nh[t] = 0;
    __syncthreads();

    unsigned val[10];
    int rk[10];
#pragma unroll
    for (int u = 0; u < 10; ++u) {
        int i = t + u * 512;
        bool p = i < bc;
        unsigned v = p ? ebuf[bb + i] : 0u;
        val[u] = v;
        rk[u] = p ? atomicAdd(&nh[v >> 17], 1) : 0;
    }
    __syncthreads();
    if (t < BSZ) sc[t] = nh[t];
    __syncthreads();
    for (int off = 1; off < BSZ; off <<= 1) {
        int v = (t < BSZ && t >= off) ? sc[t - off] : 0;
        __syncthreads();
        if (t < BSZ) sc[t] += v;
        __syncthreads();
    }
    if (t < BSZ) {
        int node = bk * BSZ + t;
        if (node < N_NODES) {
            int c = nh[t];
            cnt[node] = c;
            base[node] = bb + sc[t] - c;
            dinv[node] = rsqrtf((float)(c + 1));
        }
    }
#pragma unroll
    for (int u = 0; u < 10; ++u) {
        int i = t + u * 512;
        if (i < bc) {
            unsigned v = val[u];
            int dl = v >> 17;
            es[bb + sc[dl] - nh[dl] + rk[u]] = (int)(v & 0x1FFFFu) << 8;   // byte offset
        }
    }
}

// ---------- fused gather-aggregate + minmax scale + L2 normalize ----------
// 4 nodes per wave, 16 lanes per node, dwordx4 gathers.  hbs rows are
// UNSCALED; dinv[src] is gathered per-edge (L2-resident 400 KB) with a
// 1-iteration prefetch, broadcast via the same ds_bpermute as the row
// offset, and applied with v_pk_fma (same inner-loop instruction count).
__global__ __launch_bounds__(256) void k_agg_fin(const unsigned short* __restrict__ hbs,
                                                 const float* __restrict__ dinv,
                                                 const int* __restrict__ es,
                                                 const int* __restrict__ base,
                                                 const int* __restrict__ cnt,
                                                 const float* __restrict__ b,
                                                 float* __restrict__ out) {
    int t = threadIdx.x;
    int lane = t & 63;
    int ll = lane & 15;           // lane within node group
    int node = blockIdx.x * 16 + (t >> 4);

    const char* hb = (const char*)hbs;
    const char* dvc = (const char*)dinv;
    int lane_byte = ll << 4;
    int bidx = (lane & 48) << 2;  // bpermute byte index of group's lane 0

    float dn = dinv[node];
    int d  = cnt[node];
    int st = base[node];

    float4 bv0 = ((const float4*)b)[ll * 2];
    float4 bv1 = ((const float4*)b)[ll * 2 + 1];

    // self row: contributes dinv[node] * h_self (outer dn applied at end)
    uint4 gs = *(const uint4*)(hb + ((size_t)node << 8) + lane_byte);
    float2v dself; dself.x = dn; dself.y = dn;
    float2v acc[4];
#pragma unroll
    for (int c = 0; c < 4; ++c) { acc[c].x = 0.f; acc[c].y = 0.f; }
    pkfma(acc[0], gs.x, dself); pkfma(acc[1], gs.y, dself);
    pkfma(acc[2], gs.z, dself); pkfma(acc[3], gs.w, dself);

    int dm = d;
    dm = max(dm, __shfl_xor(dm, 16, 64));
    dm = max(dm, __shfl_xor(dm, 32, 64));
    int iters = __builtin_amdgcn_readfirstlane((dm + 15) >> 4);

    const int zoff = N_NODES << 8;   // zero row byte offset

    // preload iter 0's edge offsets + source dinv
    int off = zoff; float dnv = 0.f;
    if (ll < d) {
        off = es[st + ll];
        dnv = *(const float*)(dvc + ((unsigned)off >> 6));   // dinv[src]
    }

    for (int it = 0; it < iters; ++it) {
        // prefetch next iteration (condition false on last iter since iters*16 >= d)
        int offn = zoff; float dnn = 0.f;
        int jb2 = (it + 1) << 4;
        if (jb2 + ll < d) {
            offn = es[st + jb2 + ll];
            dnn = *(const float*)(dvc + ((unsigned)offn >> 6));
        }
        int dni = __float_as_int(dnv);

        uint4 ga[4], gb[4];
        float2v da[4], db[4];
#pragma unroll
        for (int k = 0; k < 4; ++k) {
            int ro = __builtin_amdgcn_ds_bpermute(bidx + (k << 2), off);
            float f = __int_as_float(__builtin_amdgcn_ds_bpermute(bidx + (k << 2), dni));
            da[k].x = f; da[k].y = f;
            ga[k] = *(const uint4*)(hb + (unsigned)(ro + lane_byte));
        }
#pragma unroll
        for (int k = 0; k < 4; ++k) {
            int ro = __builtin_amdgcn_ds_bpermute(bidx + ((4 + k) << 2), off);
            float f = __int_as_float(__builtin_amdgcn_ds_bpermute(bidx + ((4 + k) << 2), dni));
            db[k].x = f; db[k].y = f;
            gb[k] = *(const uint4*)(hb + (unsigned)(ro + lane_byte));
        }
#pragma unroll
        for (int k = 0; k < 4; ++k) {
            pkfma(acc[0], ga[k].x, da[k]); pkfma(acc[1], ga[k].y, da[k]);
            pkfma(acc[2], ga[k].z, da[k]); pkfma(acc[3], ga[k].w, da[k]);
        }
#pragma unroll
        for (int k = 0; k < 4; ++k) {
            int ro = __builtin_amdgcn_ds_bpermute(bidx + ((8 + k) << 2), off);
            float f = __int_as_float(__builtin_amdgcn_ds_bpermute(bidx + ((8 + k) << 2), dni));
            da[k].x = f; da[k].y = f;
            ga[k] = *(const uint4*)(hb + (unsigned)(ro + lane_byte));
        }
#pragma unroll
        for (int k = 0; k < 4; ++k) {
            pkfma(acc[0], gb[k].x, db[k]); pkfma(acc[1], gb[k].y, db[k]);
            pkfma(acc[2], gb[k].z, db[k]); pkfma(acc[3], gb[k].w, db[k]);
        }
#pragma unroll
        for (int k = 0; k < 4; ++k) {
            int ro = __builtin_amdgcn_ds_bpermute(bidx + ((12 + k) << 2), off);
            float f = __int_as_float(__builtin_amdgcn_ds_bpermute(bidx + ((12 + k) << 2), dni));
            db[k].x = f; db[k].y = f;
            gb[k] = *(const uint4*)(hb + (unsigned)(ro + lane_byte));
        }
#pragma unroll
        for (int k = 0; k < 4; ++k) {
            pkfma(acc[0], ga[k].x, da[k]); pkfma(acc[1], ga[k].y, da[k]);
            pkfma(acc[2], ga[k].z, da[k]); pkfma(acc[3], ga[k].w, da[k]);
        }
#pragma unroll
        for (int k = 0; k < 4; ++k) {
            pkfma(acc[0], gb[k].x, db[k]); pkfma(acc[1], gb[k].y, db[k]);
            pkfma(acc[2], gb[k].z, db[k]); pkfma(acc[3], gb[k].w, db[k]);
        }

        off = offn; dnv = dnn;
    }

    float v[8];
    v[0] = dn * acc[0].x + bv0.x;  v[1] = dn * acc[0].y + bv0.y;
    v[2] = dn * acc[1].x + bv0.z;  v[3] = dn * acc[1].y + bv0.w;
    v[4] = dn * acc[2].x + bv1.x;  v[5] = dn * acc[2].y + bv1.y;
    v[6] = dn * acc[3].x + bv1.z;  v[7] = dn * acc[3].y + bv1.w;

    float lmin = v[0], lmax = v[0];
#pragma unroll
    for (int i = 1; i < 8; ++i) { lmin = fminf(lmin, v[i]); lmax = fmaxf(lmax, v[i]); }
#pragma unroll
    for (int m = 8; m; m >>= 1) {
        lmin = fminf(lmin, __shfl_xor(lmin, m, 64));
        lmax = fmaxf(lmax, __shfl_xor(lmax, m, 64));
    }
    float scale = 1.0f / (lmax - lmin);
    float z[8];
    float ss = 0.f;
#pragma unroll
    for (int i = 0; i < 8; ++i) { z[i] = (v[i] - lmin) * scale; ss += z[i] * z[i]; }
#pragma unroll
    for (int m = 8; m; m >>= 1) ss += __shfl_xor(ss, m, 64);
    float inv = 1.0f / fmaxf(sqrtf(ss), 1e-12f);

    float4 o0 = {z[0] * inv, z[1] * inv, z[2] * inv, z[3] * inv};
    float4 o1 = {z[4] * inv, z[5] * inv, z[6] * inv, z[7] * inv};
    float4* op = (float4*)(out + (size_t)node * OUT_CH);
    op[ll * 2] = o0;
    op[ll * 2 + 1] = o1;
}

extern "C" void kernel_launch(void* const* d_in, const int* in_sizes, int n_in,
                              void* d_out, int out_size, void* d_ws, size_t ws_size,
                              hipStream_t stream) {
    const float* x = (const float*)d_in[0];        // fp32 [N, 256]
    const int* ei = (const int*)d_in[1];           // int32 [2, E]
    const float* W = (const float*)d_in[2];        // fp32 [256, 128]
    const float* b = (const float*)d_in[3];        // fp32 [128]
    float* out = (float*)d_out;                    // fp32 [N, 128]

    char* ws = (char*)d_ws;
    size_t o = 0;
    auto alloc = [&](size_t bytes) { void* p = ws + o; o = (o + bytes + 255) & ~(size_t)255; return p; };
    float* dinv    = (float*)alloc((size_t)N_NODES * 4);
    int*   cnt     = (int*)  alloc((size_t)N_NODES * 4);
    int*   base    = (int*)  alloc((size_t)N_NODES * 4);
    int*   bcursor = (int*)  alloc(NBUCK * 4);
    unsigned short* wb_hi = (unsigned short*)alloc((size_t)IN_CH * OUT_CH * 2);
    unsigned short* wb_lo = (unsigned short*)alloc((size_t)IN_CH * OUT_CH * 2);
    unsigned short* hbs = (unsigned short*)alloc((size_t)(N_NODES + 1) * OUT_CH * 2);  // +1 zero row
    unsigned* ebuf = (unsigned*)alloc((size_t)NBUCK * BCAP * 4);
    int*   es      = (int*)  alloc((size_t)NBUCK * BCAP * 4);

    const int* rows = ei;
    const int* cols = ei + N_EDGES;

    // init: W prep + zero bcursor + zero row (replaces both memsets)
    k_init<<<PREPB, 512, 0, stream>>>(W, wb_hi, wb_lo, bcursor,
                                      (unsigned*)(hbs + (size_t)N_NODES * OUT_CH));

    // fused: edge scatter || GEMM (independent; overlap in one launch)
    k_main<<<SCB + GEMB, 512, 0, stream>>>(rows, cols, bcursor, ebuf,
                                           x, wb_hi, wb_lo, hbs);

    // per-bucket fine sort + cnt/base/dinv
    pb_build<<<NBUCK, 512, 0, stream>>>(ebuf, bcursor, cnt, base, dinv, es);

    // fused aggregate + scale + normalize (per-edge dinv)
    k_agg_fin<<<N_NODES / 16, 256, 0, stream>>>(hbs, dinv, es, base, cnt, b, out);
}